// Round 9
// baseline (1986.508 us; speedup 1.0000x reference)
//
#include <hip/hip_runtime.h>

#define EPSV 1e-4f

// Level geometry (derived from reference shapes)
constexpr int D1=41, H1=264, W1=264; constexpr int S1=D1*H1*W1;   // 2,857,536
constexpr int D2=20, H2=131, W2=131; constexpr int S2=D2*H2*W2;   //   343,220
constexpr int D3=9,  H3=65,  W3=65;  constexpr int S3=D3*H3*W3;   //    38,025
constexpr int D4=4,  H4=32,  W4=32;  constexpr int S4=D4*H4*W4;   //     4,096
constexpr int DO_=2, HO_=32, WO_=32; constexpr int SO_=DO_*HO_*WO_; //   2,048
constexpr int NVOX_MAX=80000;

// ---- scatter voxel indices into dense grid; last-write-wins == max index (matches np) ----
__global__ void scatter_k(const int* __restrict__ coords, int n, int* __restrict__ grid1){
  int i = blockIdx.x*blockDim.x + threadIdx.x;
  if (i >= n) return;
  int z = coords[i*4+1], y = coords[i*4+2], x = coords[i*4+3];
  atomicMax(&grid1[(z*H1 + y)*W1 + x], i);
}

// ---- compact active sites of level 1 (block-aggregated atomics) ----
__global__ void compact1_k(int* __restrict__ grid1, int* __restrict__ act,
                           int* __restrict__ vox, int* __restrict__ cnt){
  __shared__ int lcnt, lbase;
  if (threadIdx.x == 0) lcnt = 0;
  __syncthreads();
  int p = blockIdx.x*blockDim.x + threadIdx.x;
  int v = (p < S1) ? grid1[p] : -1;
  int loc = -1;
  if (v >= 0) loc = atomicAdd(&lcnt, 1);
  __syncthreads();
  if (threadIdx.x == 0) lbase = (lcnt > 0) ? atomicAdd(cnt, lcnt) : 0;
  __syncthreads();
  if (v >= 0){
    int r = lbase + loc;
    act[r] = p; vox[r] = v; grid1[p] = r;
  }
}

// ---- gather winning voxel features into compact rows (Cin=4 -> float4) ----
__global__ void gather0_k(const float4* __restrict__ vf, const int* __restrict__ vox,
                          const int* __restrict__ cnt, float4* __restrict__ f0){
  int r = blockIdx.x*blockDim.x + threadIdx.x;
  if (r >= *cnt) return;
  f0[r] = vf[vox[r]];
}

// 16 FMAs on float4 registers: acc[j] += f[i] * w_i[j]
#define FMA4(acc, f, w0, w1, w2, w3)                      \
  acc.x = fmaf(f.x, w0.x, acc.x); acc.y = fmaf(f.x, w0.y, acc.y); \
  acc.z = fmaf(f.x, w0.z, acc.z); acc.w = fmaf(f.x, w0.w, acc.w); \
  acc.x = fmaf(f.y, w1.x, acc.x); acc.y = fmaf(f.y, w1.y, acc.y); \
  acc.z = fmaf(f.y, w1.z, acc.z); acc.w = fmaf(f.y, w1.w, acc.w); \
  acc.x = fmaf(f.z, w2.x, acc.x); acc.y = fmaf(f.z, w2.y, acc.y); \
  acc.z = fmaf(f.z, w2.z, acc.z); acc.w = fmaf(f.z, w2.w, acc.w); \
  acc.x = fmaf(f.w, w3.x, acc.x); acc.y = fmaf(f.w, w3.y, acc.y); \
  acc.z = fmaf(f.w, w3.z, acc.z); acc.w = fmaf(f.w, w3.w, acc.w)

template<int COUT>
__device__ __forceinline__ void bn_relu_store(float* __restrict__ fout, int r, int co,
                                              const float* __restrict__ bnp, float4 acc){
  float4 g = *(const float4*)(bnp + co);
  float4 b = *(const float4*)(bnp + COUT + co);
  float4 m = *(const float4*)(bnp + 2*COUT + co);
  float4 v = *(const float4*)(bnp + 3*COUT + co);
  float4 o;
  o.x = fmaxf((acc.x - m.x) * (g.x * rsqrtf(v.x + EPSV)) + b.x, 0.f);
  o.y = fmaxf((acc.y - m.y) * (g.y * rsqrtf(v.y + EPSV)) + b.y, 0.f);
  o.z = fmaxf((acc.z - m.z) * (g.z * rsqrtf(v.z + EPSV)) + b.z, 0.f);
  o.w = fmaxf((acc.w - m.w) * (g.w * rsqrtf(v.w + EPSV)) + b.w, 0.f);
  *(float4*)(fout + (size_t)r*COUT + co) = o;
}

// ==== sparse/subm conv: lane = 2 sites, wave = cout-quad (scalar-path weights),
//      feature double-buffer pipeline (granule = 16 cin), grid prefetch 2 taps
//      ahead, zero barriers ====
template<int CIN,int COUT,bool SUBM,int DI,int HI,int WI,int HOo,int WOo,
         int SD,int SH,int SW>
__global__ __launch_bounds__(256,4) void conv_sw_k(
    const float* __restrict__ fin, const float* __restrict__ w,
    const float* __restrict__ bnp, const int* __restrict__ grid,
    const int* __restrict__ act, const int* __restrict__ cnt,
    float* __restrict__ fout)
{
  constexpr int NT  = 27;
  constexpr int NCO = 4;               // couts per lane (one float4 acc per site)
  constexpr int NCG = COUT/NCO;        // cout groups per site-block
  constexpr int FQ  = (CIN >= 16) ? 4 : CIN/4;  // float4s per site per granule
  constexpr int NH  = CIN/(4*FQ);      // granules per tap (1,2,4)
  const int lane = threadIdx.x & 63;
  const int wgl  = blockIdx.x*4 + (threadIdx.x >> 6);
  const int sblk = wgl / NCG;
  const int cg   = wgl % NCG;
  int co = __builtin_amdgcn_readfirstlane(cg*NCO);   // weights -> scalar path
  const int n = *cnt;
  if (sblk*128 >= n) return;           // wave-uniform exit
  const int rA = sblk*128 + lane;
  const int rB = rA + 64;
  const bool okA = rA < n, okB = rB < n;

  int zA=0,yA=0,xA=0, zB=0,yB=0,xB=0;
  if (okA){ int p = act[rA]; xA = p % WOo; int t1 = p/WOo; yA = t1 % HOo; zA = t1/HOo; }
  if (okB){ int p = act[rB]; xB = p % WOo; int t2 = p/WOo; yB = t2 % HOo; zB = t2/HOo; }

  auto gidx = [&](int kk, int rSelf, int z, int y, int x, bool ok)->int {
    if (!ok || kk >= NT) return -1;
    int kd = kk/9, kh = (kk/3)%3, kw2 = kk%3;
    if (SUBM){
      if (kk == 13) return rSelf;            // center tap = self
      int zz = z + kd - 1, yy = y + kh - 1, xx = x + kw2 - 1;
      if ((unsigned)zz >= (unsigned)DI || (unsigned)yy >= (unsigned)HI ||
          (unsigned)xx >= (unsigned)WI) return -1;
      return grid[(zz*HI + yy)*WI + xx];
    } else {
      int zz = z*SD + kd, yy = y*SH + kh, xx = x*SW + kw2;  // VALID: in bounds
      return grid[(zz*HI + yy)*WI + xx];
    }
  };
  auto gA = [&](int kk){ return gidx(kk, rA, zA, yA, xA, okA); };
  auto gB = [&](int kk){ return gidx(kk, rB, zB, yB, xB, okB); };

  float4 accA = {0.f,0.f,0.f,0.f}, accB = {0.f,0.f,0.f,0.f};
  float4 bufXA[FQ], bufXB[FQ], bufYA[FQ], bufYB[FQ];

  auto loadF = [&](float4* buf, int rr, int c4base){
    if (rr >= 0){
      const float4* fi = (const float4*)(fin + (size_t)rr*CIN) + c4base;
      #pragma unroll
      for (int q = 0; q < FQ; q++) buf[q] = fi[q];
    }
  };
  auto fmaG = [&](const float4* bA, const float4* bB, int rrA, int rrB, int kk, int c4base){
    const float* wt = w + ((size_t)kk*CIN + (size_t)c4base*4)*COUT + co;  // uniform
    #pragma unroll
    for (int q = 0; q < FQ; q++){
      const float* wq = wt + q*4*COUT;
      float4 w0 = *(const float4*)(wq);
      float4 w1 = *(const float4*)(wq + COUT);
      float4 w2 = *(const float4*)(wq + 2*COUT);
      float4 w3 = *(const float4*)(wq + 3*COUT);
      if (rrA >= 0){ float4 f = bA[q]; FMA4(accA, f, w0, w1, w2, w3); }
      if (rrB >= 0){ float4 f = bB[q]; FMA4(accB, f, w0, w1, w2, w3); }
    }
  };

  int rrA0 = gA(0), rrB0 = gB(0);
  int rrA1 = gA(1), rrB1 = gB(1);
  loadF(bufXA, rrA0, 0); loadF(bufXB, rrB0, 0);   // prologue: granule (tap0, h0)

  if constexpr (NH == 1){
    // tap-pair ping-pong: 13 pairs + epilogue tap 26
    int rrA2, rrB2, rrA3, rrB3;
    #pragma unroll 1
    for (int t = 0; t < 13; t++){
      const int kk = 2*t;
      rrA2 = gA(kk+2); rrB2 = gB(kk+2);
      rrA3 = gA(kk+3); rrB3 = gB(kk+3);
      loadF(bufYA, rrA1, 0); loadF(bufYB, rrB1, 0);       // tap kk+1
      fmaG(bufXA, bufXB, rrA0, rrB0, kk, 0);               // tap kk
      loadF(bufXA, rrA2, 0); loadF(bufXB, rrB2, 0);       // tap kk+2
      fmaG(bufYA, bufYB, rrA1, rrB1, kk+1, 0);             // tap kk+1
      rrA0 = rrA2; rrB0 = rrB2; rrA1 = rrA3; rrB1 = rrB3;
    }
    fmaG(bufXA, bufXB, rrA0, rrB0, 26, 0);
  } else {
    // within-tap granule ping-pong (NH even: 2 or 4)
    #pragma unroll 1
    for (int kk = 0; kk < NT; kk++){
      int rrA2 = gA(kk+2), rrB2 = gB(kk+2);
      #pragma unroll
      for (int h = 0; h < NH; h += 2){
        // granule h from X; load granule h+1 into Y
        loadF(bufYA, rrA0, (h+1)*FQ); loadF(bufYB, rrB0, (h+1)*FQ);
        fmaG(bufXA, bufXB, rrA0, rrB0, kk, h*FQ);
        // granule h+1 from Y; load next granule (same tap or next tap g0) into X
        int nA  = (h+2 < NH) ? rrA0 : rrA1;
        int nB  = (h+2 < NH) ? rrB0 : rrB1;
        int nc4 = (h+2 < NH) ? (h+2)*FQ : 0;
        loadF(bufXA, nA, nc4); loadF(bufXB, nB, nc4);
        fmaG(bufYA, bufYB, rrA0, rrB0, kk, (h+1)*FQ);
      }
      rrA0 = rrA1; rrA1 = rrA2; rrB0 = rrB1; rrB1 = rrB2;
    }
  }

  if (okA) bn_relu_store<COUT>(fout, rA, co, bnp, accA);
  if (okB) bn_relu_store<COUT>(fout, rB, co, bnp, accB);
}

// ---- build downsampled active list (block-aggregated atomics) ----
template<int DI,int HI,int WI,int DDo,int HHo,int WWo,int KD,int KH,int KW,int SD,int SH,int SW>
__global__ void build_k(const int* __restrict__ gin, int* __restrict__ gout,
                        int* __restrict__ act, int* __restrict__ cnt){
  __shared__ int lcnt, lbase;
  if (threadIdx.x == 0) lcnt = 0;
  __syncthreads();
  int p = blockIdx.x*blockDim.x + threadIdx.x;
  bool any = false;
  if (p < DDo*HHo*WWo){
    int x = p % WWo; int rem = p / WWo; int y = rem % HHo; int z = rem / HHo;
    for (int kd = 0; kd < KD; kd++)
      for (int kh = 0; kh < KH; kh++)
        for (int kw = 0; kw < KW; kw++){
          if (gin[((z*SD+kd)*HI + (y*SH+kh))*WI + (x*SW+kw)] >= 0) any = true;
        }
  }
  int loc = -1;
  if (any) loc = atomicAdd(&lcnt, 1);
  __syncthreads();
  if (threadIdx.x == 0) lbase = (lcnt > 0) ? atomicAdd(cnt, lcnt) : 0;
  __syncthreads();
  if (p < DDo*HHo*WWo){
    int r = any ? (lbase + loc) : -1;
    if (any) act[r] = p;
    gout[p] = r;
  }
}

// ---- final conv (3,1,1) stride 1 VALID, dense output; 4 couts/thread ----
template<int CIN,int COUT>
__device__ __forceinline__ void accum_tap(const float* __restrict__ fin, int rr,
                                          const float* __restrict__ wtap, int co,
                                          float4& acc){
  const float4* fi = (const float4*)(fin + (size_t)rr*CIN);
  const float* wp = wtap + co;
  #pragma unroll 4
  for (int c4 = 0; c4 < CIN/4; c4++){
    float4 f  = fi[c4];
    const float* wq = wp + (size_t)c4*4*COUT;
    float4 w0 = *(const float4*)(wq);
    float4 w1 = *(const float4*)(wq + COUT);
    float4 w2 = *(const float4*)(wq + 2*COUT);
    float4 w3 = *(const float4*)(wq + 3*COUT);
    FMA4(acc, f, w0, w1, w2, w3);
  }
}

__global__ __launch_bounds__(256) void out_conv_k(
    const float* __restrict__ f4, const float* __restrict__ w,
    const float* __restrict__ bnp, const int* __restrict__ g4,
    float* __restrict__ out){
  int t = blockIdx.x*blockDim.x + threadIdx.x;
  if (t >= SO_*32) return;
  int co = (t % 32)*4; int p = t / 32;
  int x = p % WO_; int rem = p / WO_; int y = rem % HO_; int z = rem / HO_;
  bool any = false; float4 acc = {0.f,0.f,0.f,0.f};
  for (int kd = 0; kd < 3; kd++){
    int rr = g4[((z+kd)*H4 + y)*W4 + x];
    if (rr < 0) continue;
    any = true;
    accum_tap<64,128>(f4, rr, w + (size_t)kd*64*128, co, acc);
  }
  float4 o = {0.f,0.f,0.f,0.f};
  if (any){
    float4 g = *(const float4*)(bnp + co);
    float4 b = *(const float4*)(bnp + 128 + co);
    float4 m = *(const float4*)(bnp + 2*128 + co);
    float4 v = *(const float4*)(bnp + 3*128 + co);
    o.x = fmaxf((acc.x - m.x) * (g.x * rsqrtf(v.x + EPSV)) + b.x, 0.f);
    o.y = fmaxf((acc.y - m.y) * (g.y * rsqrtf(v.y + EPSV)) + b.y, 0.f);
    o.z = fmaxf((acc.z - m.z) * (g.z * rsqrtf(v.z + EPSV)) + b.z, 0.f);
    o.w = fmaxf((acc.w - m.w) * (g.w * rsqrtf(v.w + EPSV)) + b.w, 0.f);
  }
  *(float4*)(out + (size_t)p*128 + co) = o;
}

extern "C" void kernel_launch(void* const* d_in, const int* in_sizes, int n_in,
                              void* d_out, int out_size, void* d_ws, size_t ws_size,
                              hipStream_t stream){
  const float* vf  = (const float*)d_in[0];
  const int*   vc  = (const int*)  d_in[1];
  const float* w1a = (const float*)d_in[2];  const float* bn1a = (const float*)d_in[3];
  const float* w1b = (const float*)d_in[4];  const float* bn1b = (const float*)d_in[5];
  const float* w2a = (const float*)d_in[6];  const float* bn2a = (const float*)d_in[7];
  const float* w2b = (const float*)d_in[8];  const float* bn2b = (const float*)d_in[9];
  const float* w3a = (const float*)d_in[10]; const float* bn3a = (const float*)d_in[11];
  const float* w3b = (const float*)d_in[12]; const float* bn3b = (const float*)d_in[13];
  const float* w4a = (const float*)d_in[14]; const float* bn4a = (const float*)d_in[15];
  const float* w4b = (const float*)d_in[16]; const float* bn4b = (const float*)d_in[17];
  const float* wo  = (const float*)d_in[18]; const float* bno  = (const float*)d_in[19];
  float* outp = (float*)d_out;
  int nvox = in_sizes[0] / 4;
  if (nvox > NVOX_MAX) nvox = NVOX_MAX;

  char* ws = (char*)d_ws;
  size_t off = 0;
  auto alloc = [&](size_t bytes)->void*{
    void* p = ws + off; off = (off + bytes + 255) & ~size_t(255); return p;
  };
  int* grid1 = (int*)alloc((size_t)S1*4);
  int* act1  = (int*)alloc((size_t)NVOX_MAX*4);
  int* vox1  = (int*)alloc((size_t)NVOX_MAX*4);
  int* grid2 = (int*)alloc((size_t)S2*4);
  int* act2  = (int*)alloc((size_t)S2*4);
  int* grid3 = (int*)alloc((size_t)S3*4);
  int* act3  = (int*)alloc((size_t)S3*4);
  int* grid4 = (int*)alloc((size_t)S4*4);
  int* act4  = (int*)alloc((size_t)S4*4);
  int* cnt   = (int*)alloc(8*4);
  float* f0  = (float*)alloc((size_t)NVOX_MAX*4*4);
  float* f1a = (float*)alloc((size_t)NVOX_MAX*16*4);
  float* f1b = (float*)alloc((size_t)NVOX_MAX*16*4);
  float* f2a = (float*)alloc((size_t)S2*32*4);
  float* f2b = (float*)alloc((size_t)S2*32*4);
  float* f3a = (float*)alloc((size_t)S3*64*4);
  float* f3b = (float*)alloc((size_t)S3*64*4);
  float* f4a = (float*)alloc((size_t)S4*64*4);
  float* f4b = (float*)alloc((size_t)S4*64*4);
  (void)ws_size;

  hipMemsetAsync(grid1, 0xFF, (size_t)S1*4, stream);  // -1 everywhere
  hipMemsetAsync(cnt, 0, 8*4, stream);

  const int BS = 256;
  scatter_k<<<(nvox+BS-1)/BS, BS, 0, stream>>>(vc, nvox, grid1);
  compact1_k<<<(S1+BS-1)/BS, BS, 0, stream>>>(grid1, act1, vox1, &cnt[0]);
  gather0_k<<<(nvox+BS-1)/BS, BS, 0, stream>>>((const float4*)vf, vox1, &cnt[0], (float4*)f0);

  // blocks = ceil( ceil(maxN/128) * (COUT/4) / 4 )
  auto nblk = [](int maxN, int cout){ int waves = ((maxN+127)/128) * (cout/4); return (waves+3)/4; };

  // level 1 (COUT=16)
  conv_sw_k<4,16,true,D1,H1,W1,H1,W1,1,1,1>
    <<<nblk(NVOX_MAX,16), BS, 0, stream>>>(f0,  w1a, bn1a, grid1, act1, &cnt[0], f1a);
  conv_sw_k<16,16,true,D1,H1,W1,H1,W1,1,1,1>
    <<<nblk(NVOX_MAX,16), BS, 0, stream>>>(f1a, w1b, bn1b, grid1, act1, &cnt[0], f1b);

  build_k<D1,H1,W1,D2,H2,W2,3,3,3,2,2,2><<<(S2+BS-1)/BS, BS, 0, stream>>>(grid1, grid2, act2, &cnt[1]);
  // level 2 (COUT=32)
  conv_sw_k<16,32,false,D1,H1,W1,H2,W2,2,2,2>
    <<<nblk(S2,32), BS, 0, stream>>>(f1b, w2a, bn2a, grid1, act2, &cnt[1], f2a);
  conv_sw_k<32,32,true,D2,H2,W2,H2,W2,1,1,1>
    <<<nblk(S2,32), BS, 0, stream>>>(f2a, w2b, bn2b, grid2, act2, &cnt[1], f2b);

  build_k<D2,H2,W2,D3,H3,W3,3,3,3,2,2,2><<<(S3+BS-1)/BS, BS, 0, stream>>>(grid2, grid3, act3, &cnt[2]);
  // level 3 (COUT=64)
  conv_sw_k<32,64,false,D2,H2,W2,H3,W3,2,2,2>
    <<<nblk(S3,64), BS, 0, stream>>>(f2b, w3a, bn3a, grid2, act3, &cnt[2], f3a);
  conv_sw_k<64,64,true,D3,H3,W3,H3,W3,1,1,1>
    <<<nblk(S3,64), BS, 0, stream>>>(f3a, w3b, bn3b, grid3, act3, &cnt[2], f3b);

  build_k<D3,H3,W3,D4,H4,W4,3,3,3,2,2,2><<<(S4+BS-1)/BS, BS, 0, stream>>>(grid3, grid4, act4, &cnt[3]);
  // level 4 (COUT=64)
  conv_sw_k<64,64,false,D3,H3,W3,H4,W4,2,2,2>
    <<<nblk(S4,64), BS, 0, stream>>>(f3b, w4a, bn4a, grid3, act4, &cnt[3], f4a);
  conv_sw_k<64,64,true,D4,H4,W4,H4,W4,1,1,1>
    <<<nblk(S4,64), BS, 0, stream>>>(f4a, w4b, bn4b, grid4, act4, &cnt[3], f4b);

  out_conv_k<<<(SO_*32+BS-1)/BS, BS, 0, stream>>>(f4b, wo, bno, grid4, outp);
}

// Round 11
// 687.568 us; speedup vs baseline: 2.8892x; 2.8892x over previous
//
#include <hip/hip_runtime.h>

#define EPSV 1e-4f

typedef short bf16x8 __attribute__((ext_vector_type(8)));
typedef float f32x4 __attribute__((ext_vector_type(4)));

// Level geometry
constexpr int D1=41, H1=264, W1=264; constexpr int S1=D1*H1*W1;
constexpr int D2=20, H2=131, W2=131; constexpr int S2=D2*H2*W2;
constexpr int D3=9,  H3=65,  W3=65;  constexpr int S3=D3*H3*W3;
constexpr int D4=4,  H4=32,  W4=32;  constexpr int S4=D4*H4*W4;
constexpr int DO_=2, HO_=32, WO_=32; constexpr int SO_=DO_*HO_*WO_;
constexpr int NVOX_MAX=80000;

__device__ __forceinline__ unsigned short bf_rne(float f){
  unsigned int x = __float_as_uint(f);
  unsigned int r = (x + 0x7FFFu + ((x>>16)&1u)) >> 16;
  return (unsigned short)r;
}
__device__ __forceinline__ float bf_tof(unsigned short u){
  return __uint_as_float(((unsigned int)u)<<16);
}

// ---- scatter: last-write-wins == max voxel index (matches np) ----
__global__ void scatter_k(const int* __restrict__ coords, int n, int* __restrict__ grid1){
  int i = blockIdx.x*blockDim.x + threadIdx.x;
  if (i >= n) return;
  int z = coords[i*4+1], y = coords[i*4+2], x = coords[i*4+3];
  atomicMax(&grid1[(z*H1 + y)*W1 + x], i);
}

__global__ void compact1_k(int* __restrict__ grid1, int* __restrict__ act,
                           int* __restrict__ vox, int* __restrict__ cnt){
  __shared__ int lcnt, lbase;
  if (threadIdx.x == 0) lcnt = 0;
  __syncthreads();
  int p = blockIdx.x*blockDim.x + threadIdx.x;
  int v = (p < S1) ? grid1[p] : -1;
  int loc = -1;
  if (v >= 0) loc = atomicAdd(&lcnt, 1);
  __syncthreads();
  if (threadIdx.x == 0) lbase = (lcnt > 0) ? atomicAdd(cnt, lcnt) : 0;
  __syncthreads();
  if (v >= 0){ int r = lbase + loc; act[r] = p; vox[r] = v; grid1[p] = r; }
}

__global__ void gather0_k(const float4* __restrict__ vf, const int* __restrict__ vox,
                          const int* __restrict__ cnt, float4* __restrict__ f0){
  int r = blockIdx.x*blockDim.x + threadIdx.x;
  if (r >= *cnt) return;
  f0[r] = vf[vox[r]];
}

#define FMA4(acc, f, w0, w1, w2, w3)                      \
  acc.x = fmaf(f.x, w0.x, acc.x); acc.y = fmaf(f.x, w0.y, acc.y); \
  acc.z = fmaf(f.x, w0.z, acc.z); acc.w = fmaf(f.x, w0.w, acc.w); \
  acc.x = fmaf(f.y, w1.x, acc.x); acc.y = fmaf(f.y, w1.y, acc.y); \
  acc.z = fmaf(f.y, w1.z, acc.z); acc.w = fmaf(f.y, w1.w, acc.w); \
  acc.x = fmaf(f.z, w2.x, acc.x); acc.y = fmaf(f.z, w2.y, acc.y); \
  acc.z = fmaf(f.z, w2.z, acc.z); acc.w = fmaf(f.z, w2.w, acc.w); \
  acc.x = fmaf(f.w, w3.x, acc.x); acc.y = fmaf(f.w, w3.y, acc.y); \
  acc.z = fmaf(f.w, w3.z, acc.z); acc.w = fmaf(f.w, w3.w, acc.w)

// ==== VALU sparse/subm conv (R6 structure): lane=site, wave=cout-group of 8,
//      scalar-path weights, grid prefetch 2 taps ahead. HLOUT -> bf16 hi/lo rows.
template<int CIN,int COUT,bool SUBM,int DI,int HI,int WI,int HOo,int WOo,
         int SD,int SH,int SW,bool HLOUT>
__global__ __launch_bounds__(256) void conv_sw_k(
    const float* __restrict__ fin, const float* __restrict__ w,
    const float* __restrict__ bnp, const int* __restrict__ grid,
    const int* __restrict__ act, const int* __restrict__ cnt,
    void* __restrict__ fout_v)
{
  constexpr int NT  = 27;
  constexpr int NCO = 8;
  constexpr int NCG = COUT/NCO;
  const int lane = threadIdx.x & 63;
  const int wgl  = blockIdx.x*4 + (threadIdx.x >> 6);
  const int sblk = wgl / NCG;
  const int cg   = wgl % NCG;
  int co = __builtin_amdgcn_readfirstlane(cg*NCO);
  const int n = *cnt;
  if (sblk*64 >= n) return;
  const int r = sblk*64 + lane;
  const bool ok = r < n;

  int z=0, y=0, x=0;
  if (ok){ int p = act[r]; x = p % WOo; int t1 = p/WOo; y = t1 % HOo; z = t1/HOo; }

  auto gidx = [&](int kk)->int {
    if (!ok) return -1;
    int kd = kk/9, kh = (kk/3)%3, kw2 = kk%3;
    if (SUBM){
      if (kk == 13) return r;
      int zz = z + kd - 1, yy = y + kh - 1, xx = x + kw2 - 1;
      if ((unsigned)zz >= (unsigned)DI || (unsigned)yy >= (unsigned)HI ||
          (unsigned)xx >= (unsigned)WI) return -1;
      return grid[(zz*HI + yy)*WI + xx];
    } else {
      int zz = z*SD + kd, yy = y*SH + kh, xx = x*SW + kw2;
      return grid[(zz*HI + yy)*WI + xx];
    }
  };

  float4 acc0 = {0.f,0.f,0.f,0.f}, acc1 = {0.f,0.f,0.f,0.f};
  int rr0 = gidx(0);
  int rr1 = gidx(1);
  #pragma unroll 1
  for (int kk = 0; kk < NT; kk++){
    int rrn = (kk + 2 < NT) ? gidx(kk+2) : -1;
    if (rr0 >= 0){
      const float4* fi = (const float4*)(fin + (size_t)rr0*CIN);
      const float* wt = w + (size_t)kk*CIN*COUT + co;
      #pragma unroll 8
      for (int c4 = 0; c4 < CIN/4; c4++){
        float4 f  = fi[c4];
        const float* wq = wt + c4*4*COUT;
        {
          float4 w0 = *(const float4*)(wq);
          float4 w1 = *(const float4*)(wq + COUT);
          float4 w2 = *(const float4*)(wq + 2*COUT);
          float4 w3 = *(const float4*)(wq + 3*COUT);
          FMA4(acc0, f, w0, w1, w2, w3);
        }
        {
          float4 w0 = *(const float4*)(wq + 4);
          float4 w1 = *(const float4*)(wq + COUT + 4);
          float4 w2 = *(const float4*)(wq + 2*COUT + 4);
          float4 w3 = *(const float4*)(wq + 3*COUT + 4);
          FMA4(acc1, f, w0, w1, w2, w3);
        }
      }
    }
    rr0 = rr1; rr1 = rrn;
  }
  if (ok){
    float o[8];
    float av[8] = {acc0.x,acc0.y,acc0.z,acc0.w, acc1.x,acc1.y,acc1.z,acc1.w};
    #pragma unroll
    for (int k = 0; k < 8; k++){
      int c = co + k;
      float g = bnp[c], b = bnp[COUT+c], m = bnp[2*COUT+c], v = bnp[3*COUT+c];
      o[k] = fmaxf((av[k] - m) * (g * rsqrtf(v + EPSV)) + b, 0.f);
    }
    if constexpr (HLOUT){
      unsigned short* fout = (unsigned short*)fout_v;
      bf16x8 vh, vl;
      #pragma unroll
      for (int k = 0; k < 8; k++){
        unsigned short hi = bf_rne(o[k]);
        vh[k] = (short)hi;
        vl[k] = (short)bf_rne(o[k] - bf_tof(hi));
      }
      *(bf16x8*)(fout + (size_t)r*2*COUT + co) = vh;
      *(bf16x8*)(fout + (size_t)r*2*COUT + COUT + co) = vl;
    } else {
      float* fout = (float*)fout_v;
      float4 o0 = {o[0],o[1],o[2],o[3]}, o1 = {o[4],o[5],o[6],o[7]};
      *(float4*)(fout + (size_t)r*COUT + co) = o0;
      *(float4*)(fout + (size_t)r*COUT + co + 4) = o1;
    }
  }
}

// ---- weight prep: fp32 [27][CIN][COUT] -> bf16 hi/lo packed in B-fragment order
//      flat idx = ((c*COUT + n)*4 + kgrp)*8 + j ; k = c*32 + kgrp*8 + j
__global__ void wprep_k(const float* __restrict__ w, unsigned short* __restrict__ whi,
                        unsigned short* __restrict__ wlo, int CIN_, int COUT_, int NK_){
  int tid = blockIdx.x*256 + threadIdx.x;
  int total = NK_*COUT_*32;
  if (tid >= total) return;
  int j = tid & 7; int kgrp = (tid>>3)&3; int rest = tid>>5;
  int nn = rest % COUT_; int c = rest / COUT_;
  int kflat = c*32 + kgrp*8 + j;
  int tap = kflat / CIN_; int cin = kflat % CIN_;
  float val = w[((size_t)tap*CIN_ + cin)*COUT_ + nn];
  unsigned short hi = bf_rne(val);
  whi[tid] = hi;
  wlo[tid] = bf_rne(val - bf_tof(hi));
}

// ==== MFMA implicit-GEMM sparse/subm conv, bf16 hi/lo split (3-pass) ====
// Block: 64 sites x COUT. 4 waves. Input/output rows: [hi CIN | lo CIN] bf16.
template<int CIN,int COUT,bool SUBM,int DI,int HI,int WI,int HOo,int WOo,
         int SD,int SH,int SW>
__global__ __launch_bounds__(256) void conv_mfma_k(
    const unsigned short* __restrict__ fin, const unsigned short* __restrict__ wBhi,
    const unsigned short* __restrict__ wBlo, const float* __restrict__ bnp,
    const int* __restrict__ grid, const int* __restrict__ act,
    const int* __restrict__ cnt, unsigned short* __restrict__ fout)
{
  constexpr int NK  = 27*CIN/32;   // K chunks of 32
  constexpr int NTN = COUT/16;     // n-tiles in block
  constexpr int MT  = NTN;         // m-tiles per wave (4 waves cover 4 x NTN tiles)
  constexpr int LDA = 40;          // ushort stride per A row (32 + 8 pad -> 80B)
  __shared__ int act_lds[64];
  __shared__ int rr_lds[27*64];
  __shared__ unsigned short AhiL[2][64*LDA];
  __shared__ unsigned short AloL[2][64*LDA];

  const int tid  = threadIdx.x;
  const int lane = tid & 63;
  const int wv   = tid >> 6;
  const int blk  = blockIdx.x;
  const int n    = *cnt;
  if (blk*64 >= n) return;

  if (tid < 64){
    int r = blk*64 + tid;
    act_lds[tid] = (r < n) ? act[r] : -1;
  }
  __syncthreads();
  for (int idx = tid; idx < 27*64; idx += 256){
    int s = idx & 63, tap = idx >> 6;
    int p = act_lds[s];
    int rr = -1;
    if (p >= 0){
      int x = p % WOo; int t1 = p / WOo; int y = t1 % HOo; int z = t1 / HOo;
      int kd = tap/9, kh = (tap/3)%3, kw2 = tap%3;
      if (SUBM){
        if (tap == 13) rr = blk*64 + s;
        else {
          int zz = z+kd-1, yy = y+kh-1, xx = x+kw2-1;
          if ((unsigned)zz < (unsigned)DI && (unsigned)yy < (unsigned)HI &&
              (unsigned)xx < (unsigned)WI)
            rr = grid[(zz*HI+yy)*WI+xx];
        }
      } else {
        int zz = z*SD+kd, yy = y*SH+kh, xx = x*SW+kw2;
        rr = grid[(zz*HI+yy)*WI+xx];
      }
    }
    rr_lds[idx] = rr;
  }
  __syncthreads();

  const int ss = tid >> 2;          // staging site
  const int sq = tid & 3;           // staging quarter (0,1=hi; 2,3=lo)
  const bf16x8 zv = {0,0,0,0,0,0,0,0};

  auto stage_load = [&](int c, bf16x8& v0, bf16x8& v1){
    int tap = (c*32)/CIN;
    int ks  = (c*32)%CIN;
    int rr  = rr_lds[tap*64 + ss];
    if (rr >= 0){
      int eoff = (sq < 2) ? (ks + sq*16) : (CIN + ks + (sq-2)*16);
      const bf16x8* sp = (const bf16x8*)(fin + (size_t)rr*2*CIN + eoff);
      v0 = sp[0]; v1 = sp[1];
    } else { v0 = zv; v1 = zv; }
  };
  auto stage_write = [&](int b, bf16x8 v0, bf16x8 v1){
    unsigned short* base = (sq < 2) ? &AhiL[b][ss*LDA + sq*16]
                                    : &AloL[b][ss*LDA + (sq-2)*16];
    ((bf16x8*)base)[0] = v0; ((bf16x8*)base)[1] = v1;
  };

  const int nt    = wv % NTN;
  const int mbase = (wv / NTN) * MT;
  const int l15   = lane & 15;
  const int lg    = lane >> 4;

  f32x4 acc[MT];
  #pragma unroll
  for (int i = 0; i < MT; i++) acc[i] = (f32x4){0.f,0.f,0.f,0.f};

  {
    bf16x8 s0, s1;
    stage_load(0, s0, s1);
    stage_write(0, s0, s1);
  }
  __syncthreads();

  #pragma unroll 1
  for (int c = 0; c < NK; c++){
    const int b = c & 1;
    bf16x8 n0 = zv, n1 = zv;
    if (c + 1 < NK) stage_load(c+1, n0, n1);

    // B fragments (global, packed): lane -> n = nt*16+l15, kgrp = lg
    size_t bidx = ((size_t)(c*COUT + nt*16 + l15)*4 + lg) * 8;
    bf16x8 Bh = *(const bf16x8*)(wBhi + bidx);
    bf16x8 Bl = *(const bf16x8*)(wBlo + bidx);

    #pragma unroll
    for (int i = 0; i < MT; i++){
      int row = (mbase + i)*16 + l15;
      bf16x8 Ah = *(const bf16x8*)(&AhiL[b][row*LDA + lg*8]);
      bf16x8 Al = *(const bf16x8*)(&AloL[b][row*LDA + lg*8]);
      acc[i] = __builtin_amdgcn_mfma_f32_16x16x32_bf16(Ah, Bh, acc[i], 0, 0, 0);
      acc[i] = __builtin_amdgcn_mfma_f32_16x16x32_bf16(Ah, Bl, acc[i], 0, 0, 0);
      acc[i] = __builtin_amdgcn_mfma_f32_16x16x32_bf16(Al, Bh, acc[i], 0, 0, 0);
    }

    if (c + 1 < NK) stage_write(b ^ 1, n0, n1);
    __syncthreads();
  }

  // epilogue: D row = mtile*16 + (lane>>4)*4 + reg (site), col = nt*16 + (lane&15) (cout)
  const int cout = nt*16 + l15;
  const float g = bnp[cout], bb = bnp[COUT+cout];
  const float mm = bnp[2*COUT+cout], vv = bnp[3*COUT+cout];
  const float sc = g * rsqrtf(vv + EPSV);
  #pragma unroll
  for (int i = 0; i < MT; i++){
    #pragma unroll
    for (int reg = 0; reg < 4; reg++){
      int srow = (mbase + i)*16 + lg*4 + reg;
      int r = blk*64 + srow;
      if (r < n){
        float o = fmaxf((acc[i][reg] - mm) * sc + bb, 0.f);
        unsigned short hi = bf_rne(o);
        unsigned short lo = bf_rne(o - bf_tof(hi));
        fout[(size_t)r*2*COUT + cout] = hi;
        fout[(size_t)r*2*COUT + COUT + cout] = lo;
      }
    }
  }
}

// ---- build downsampled active list ----
template<int DI,int HI,int WI,int DDo,int HHo,int WWo,int KD,int KH,int KW,int SD,int SH,int SW>
__global__ void build_k(const int* __restrict__ gin, int* __restrict__ gout,
                        int* __restrict__ act, int* __restrict__ cnt){
  __shared__ int lcnt, lbase;
  if (threadIdx.x == 0) lcnt = 0;
  __syncthreads();
  int p = blockIdx.x*blockDim.x + threadIdx.x;
  bool any = false;
  if (p < DDo*HHo*WWo){
    int x = p % WWo; int rem = p / WWo; int y = rem % HHo; int z = rem / HHo;
    for (int kd = 0; kd < KD; kd++)
      for (int kh = 0; kh < KH; kh++)
        for (int kw = 0; kw < KW; kw++){
          if (gin[((z*SD+kd)*HI + (y*SH+kh))*WI + (x*SW+kw)] >= 0) any = true;
        }
  }
  int loc = -1;
  if (any) loc = atomicAdd(&lcnt, 1);
  __syncthreads();
  if (threadIdx.x == 0) lbase = (lcnt > 0) ? atomicAdd(cnt, lcnt) : 0;
  __syncthreads();
  if (p < DDo*HHo*WWo){
    int r = any ? (lbase + loc) : -1;
    if (any) act[r] = p;
    gout[p] = r;
  }
}

// ---- final conv (3,1,1) VALID, dense out; reads hi/lo bf16 f4b ----
__global__ __launch_bounds__(256) void out_conv_k(
    const unsigned short* __restrict__ f4, const float* __restrict__ w,
    const float* __restrict__ bnp, const int* __restrict__ g4,
    float* __restrict__ out){
  int t = blockIdx.x*blockDim.x + threadIdx.x;
  if (t >= SO_*32) return;
  int co = (t % 32)*4; int p = t / 32;
  int x = p % WO_; int rem = p / WO_; int y = rem % HO_; int z = rem / HO_;
  bool any = false; float4 acc = {0.f,0.f,0.f,0.f};
  for (int kd = 0; kd < 3; kd++){
    int rr = g4[((z+kd)*H4 + y)*W4 + x];
    if (rr < 0) continue;
    any = true;
    const unsigned short* row = f4 + (size_t)rr*128;
    const float* wp = w + (size_t)kd*64*128 + co;
    #pragma unroll 4
    for (int ci = 0; ci < 64; ci++){
      float f = bf_tof(row[ci]) + bf_tof(row[64+ci]);
      const float* wq = wp + (size_t)ci*128;
      acc.x = fmaf(f, wq[0], acc.x); acc.y = fmaf(f, wq[1], acc.y);
      acc.z = fmaf(f, wq[2], acc.z); acc.w = fmaf(f, wq[3], acc.w);
    }
  }
  float4 o = {0.f,0.f,0.f,0.f};
  if (any){
    float4 g = *(const float4*)(bnp + co);
    float4 b = *(const float4*)(bnp + 128 + co);
    float4 m = *(const float4*)(bnp + 2*128 + co);
    float4 v = *(const float4*)(bnp + 3*128 + co);
    o.x = fmaxf((acc.x - m.x) * (g.x * rsqrtf(v.x + EPSV)) + b.x, 0.f);
    o.y = fmaxf((acc.y - m.y) * (g.y * rsqrtf(v.y + EPSV)) + b.y, 0.f);
    o.z = fmaxf((acc.z - m.z) * (g.z * rsqrtf(v.z + EPSV)) + b.z, 0.f);
    o.w = fmaxf((acc.w - m.w) * (g.w * rsqrtf(v.w + EPSV)) + b.w, 0.f);
  }
  *(float4*)(out + (size_t)p*128 + co) = o;
}

extern "C" void kernel_launch(void* const* d_in, const int* in_sizes, int n_in,
                              void* d_out, int out_size, void* d_ws, size_t ws_size,
                              hipStream_t stream){
  const float* vf  = (const float*)d_in[0];
  const int*   vc  = (const int*)  d_in[1];
  const float* w1a = (const float*)d_in[2];  const float* bn1a = (const float*)d_in[3];
  const float* w1b = (const float*)d_in[4];  const float* bn1b = (const float*)d_in[5];
  const float* w2a = (const float*)d_in[6];  const float* bn2a = (const float*)d_in[7];
  const float* w2b = (const float*)d_in[8];  const float* bn2b = (const float*)d_in[9];
  const float* w3a = (const float*)d_in[10]; const float* bn3a = (const float*)d_in[11];
  const float* w3b = (const float*)d_in[12]; const float* bn3b = (const float*)d_in[13];
  const float* w4a = (const float*)d_in[14]; const float* bn4a = (const float*)d_in[15];
  const float* w4b = (const float*)d_in[16]; const float* bn4b = (const float*)d_in[17];
  const float* wo  = (const float*)d_in[18]; const float* bno  = (const float*)d_in[19];
  float* outp = (float*)d_out;
  int nvox = in_sizes[0] / 4;
  if (nvox > NVOX_MAX) nvox = NVOX_MAX;

  char* ws = (char*)d_ws;
  size_t off = 0;
  auto alloc = [&](size_t bytes)->void*{
    void* p = ws + off; off = (off + bytes + 255) & ~size_t(255); return p;
  };
  int* grid1 = (int*)alloc((size_t)S1*4);
  int* act1  = (int*)alloc((size_t)NVOX_MAX*4);
  int* vox1  = (int*)alloc((size_t)NVOX_MAX*4);
  int* grid2 = (int*)alloc((size_t)S2*4);
  int* act2  = (int*)alloc((size_t)S2*4);
  int* grid3 = (int*)alloc((size_t)S3*4);
  int* act3  = (int*)alloc((size_t)S3*4);
  int* grid4 = (int*)alloc((size_t)S4*4);
  int* act4  = (int*)alloc((size_t)S4*4);
  int* cnt   = (int*)alloc(8*4);
  size_t f0_b  = (size_t)NVOX_MAX*4*4;
  size_t f1_b  = (size_t)NVOX_MAX*16*4;
  size_t f2_b  = (size_t)S2*64*2;
  size_t f3_b  = (size_t)S3*128*2;
  size_t f4_b  = (size_t)S4*128*2;
  float* f0  = (float*)alloc(f0_b);
  float* f1a = (float*)alloc(f1_b);
  float* f1b = (float*)alloc(f1_b);
  unsigned short* f2a = (unsigned short*)alloc(f2_b);   // [hi32|lo32]
  unsigned short* f2b = (unsigned short*)alloc(f2_b);
  unsigned short* f3a = (unsigned short*)alloc(f3_b);   // [hi64|lo64]
  unsigned short* f3b = (unsigned short*)alloc(f3_b);
  unsigned short* f4a = (unsigned short*)alloc(f4_b);
  unsigned short* f4b = (unsigned short*)alloc(f4_b);
  // packed B-fragment weights (hi/lo)
  unsigned short* p2b_h = (unsigned short*)alloc((size_t)27*32*32*2);
  unsigned short* p2b_l = (unsigned short*)alloc((size_t)27*32*32*2);
  unsigned short* p3a_h = (unsigned short*)alloc((size_t)27*32*64*2);
  unsigned short* p3a_l = (unsigned short*)alloc((size_t)27*32*64*2);
  unsigned short* p3b_h = (unsigned short*)alloc((size_t)54*32*64*2);
  unsigned short* p3b_l = (unsigned short*)alloc((size_t)54*32*64*2);
  unsigned short* p4a_h = (unsigned short*)alloc((size_t)54*32*64*2);
  unsigned short* p4a_l = (unsigned short*)alloc((size_t)54*32*64*2);
  unsigned short* p4b_h = (unsigned short*)alloc((size_t)54*32*64*2);
  unsigned short* p4b_l = (unsigned short*)alloc((size_t)54*32*64*2);
  (void)ws_size;

  hipMemsetAsync(grid1, 0xFF, (size_t)S1*4, stream);
  hipMemsetAsync(cnt, 0, 8*4, stream);
  // Zero ALL intermediate feature buffers: rows beyond the active count are
  // readable-by-construction garbage otherwise (0xAA poison on call 1 masked
  // this; stale data from a prior replay's different atomic permutation did
  // not -> post-timing divergence in R10). Zeros = deterministic & benign.
  hipMemsetAsync(f0,  0, f0_b, stream);
  hipMemsetAsync(f1a, 0, f1_b, stream);
  hipMemsetAsync(f1b, 0, f1_b, stream);
  hipMemsetAsync(f2a, 0, f2_b, stream);
  hipMemsetAsync(f2b, 0, f2_b, stream);
  hipMemsetAsync(f3a, 0, f3_b, stream);
  hipMemsetAsync(f3b, 0, f3_b, stream);
  hipMemsetAsync(f4a, 0, f4_b, stream);
  hipMemsetAsync(f4b, 0, f4_b, stream);

  const int BS = 256;
  // weight prep (independent, launch early)
  auto wprep = [&](const float* w, unsigned short* h, unsigned short* l, int cin, int cout, int nk){
    int total = nk*cout*32;
    wprep_k<<<(total+BS-1)/BS, BS, 0, stream>>>(w, h, l, cin, cout, nk);
  };
  wprep(w2b, p2b_h, p2b_l, 32, 32, 27);
  wprep(w3a, p3a_h, p3a_l, 32, 64, 27);
  wprep(w3b, p3b_h, p3b_l, 64, 64, 54);
  wprep(w4a, p4a_h, p4a_l, 64, 64, 54);
  wprep(w4b, p4b_h, p4b_l, 64, 64, 54);

  scatter_k<<<(nvox+BS-1)/BS, BS, 0, stream>>>(vc, nvox, grid1);
  compact1_k<<<(S1+BS-1)/BS, BS, 0, stream>>>(grid1, act1, vox1, &cnt[0]);
  gather0_k<<<(nvox+BS-1)/BS, BS, 0, stream>>>((const float4*)vf, vox1, &cnt[0], (float4*)f0);

  auto nblk = [](int maxN, int cout){ int waves = ((maxN+63)/64) * (cout/8); return (waves+3)/4; };

  // level 1 (VALU, fp32)
  conv_sw_k<4,16,true,D1,H1,W1,H1,W1,1,1,1,false>
    <<<nblk(NVOX_MAX,16), BS, 0, stream>>>(f0,  w1a, bn1a, grid1, act1, &cnt[0], f1a);
  conv_sw_k<16,16,true,D1,H1,W1,H1,W1,1,1,1,false>
    <<<nblk(NVOX_MAX,16), BS, 0, stream>>>(f1a, w1b, bn1b, grid1, act1, &cnt[0], f1b);

  build_k<D1,H1,W1,D2,H2,W2,3,3,3,2,2,2><<<(S2+BS-1)/BS, BS, 0, stream>>>(grid1, grid2, act2, &cnt[1]);
  // conv2a (VALU, CIN=16) -> hi/lo bf16
  conv_sw_k<16,32,false,D1,H1,W1,H2,W2,2,2,2,true>
    <<<nblk(S2,32), BS, 0, stream>>>(f1b, w2a, bn2a, grid1, act2, &cnt[1], f2a);
  // conv2b (MFMA)
  conv_mfma_k<32,32,true,D2,H2,W2,H2,W2,1,1,1>
    <<<(S2+63)/64, BS, 0, stream>>>(f2a, p2b_h, p2b_l, bn2b, grid2, act2, &cnt[1], f2b);

  build_k<D2,H2,W2,D3,H3,W3,3,3,3,2,2,2><<<(S3+BS-1)/BS, BS, 0, stream>>>(grid2, grid3, act3, &cnt[2]);
  conv_mfma_k<32,64,false,D2,H2,W2,H3,W3,2,2,2>
    <<<(S3+63)/64, BS, 0, stream>>>(f2b, p3a_h, p3a_l, bn3a, grid2, act3, &cnt[2], f3a);
  conv_mfma_k<64,64,true,D3,H3,W3,H3,W3,1,1,1>
    <<<(S3+63)/64, BS, 0, stream>>>(f3a, p3b_h, p3b_l, bn3b, grid3, act3, &cnt[2], f3b);

  build_k<D3,H3,W3,D4,H4,W4,3,3,3,2,2,2><<<(S4+BS-1)/BS, BS, 0, stream>>>(grid3, grid4, act4, &cnt[3]);
  conv_mfma_k<64,64,false,D3,H3,W3,H4,W4,2,2,2>
    <<<(S4+63)/64, BS, 0, stream>>>(f3b, p4a_h, p4a_l, bn4a, grid3, act4, &cnt[3], f4a);
  conv_mfma_k<64,64,true,D4,H4,W4,H4,W4,1,1,1>
    <<<(S4+63)/64, BS, 0, stream>>>(f4a, p4b_h, p4b_l, bn4b, grid4, act4, &cnt[3], f4b);

  out_conv_k<<<(SO_*32+BS-1)/BS, BS, 0, stream>>>(f4b, wo, bno, grid4, outp);
}

// Round 13
// 558.841 us; speedup vs baseline: 3.5547x; 1.2303x over previous
//
#include <hip/hip_runtime.h>

#define EPSV 1e-4f

typedef short bf16x8 __attribute__((ext_vector_type(8)));
typedef float f32x4 __attribute__((ext_vector_type(4)));

// Level geometry
constexpr int D1=41, H1=264, W1=264; constexpr int S1=D1*H1*W1;
constexpr int D2=20, H2=131, W2=131; constexpr int S2=D2*H2*W2;
constexpr int D3=9,  H3=65,  W3=65;  constexpr int S3=D3*H3*W3;
constexpr int D4=4,  H4=32,  W4=32;  constexpr int S4=D4*H4*W4;
constexpr int DO_=2, HO_=32, WO_=32; constexpr int SO_=DO_*HO_*WO_;
constexpr int NVOX_MAX=80000;

__device__ __forceinline__ unsigned short bf_rne(float f){
  unsigned int x = __float_as_uint(f);
  unsigned int r = (x + 0x7FFFu + ((x>>16)&1u)) >> 16;
  return (unsigned short)r;
}
__device__ __forceinline__ float bf_tof(unsigned short u){
  return __uint_as_float(((unsigned int)u)<<16);
}

// ---- scatter: last-write-wins == max voxel index (matches np) ----
__global__ void scatter_k(const int* __restrict__ coords, int n, int* __restrict__ vgrid){
  int i = blockIdx.x*blockDim.x + threadIdx.x;
  if (i >= n) return;
  int z = coords[i*4+1], y = coords[i*4+2], x = coords[i*4+3];
  atomicMax(&vgrid[(z*H1 + y)*W1 + x], i);
}

// ---- voxel-space compaction: thread i wins iff vgrid[site]==i (80k threads,
//      replaces the 2.86M-site scan). grid1 pre-memset to -1.
__global__ void compactv_k(const int* __restrict__ coords, int n,
                           const int* __restrict__ vgrid, int* __restrict__ grid1,
                           int* __restrict__ act, int* __restrict__ vox,
                           int* __restrict__ cnt){
  int i = blockIdx.x*blockDim.x + threadIdx.x;
  if (i >= n) return;
  int z = coords[i*4+1], y = coords[i*4+2], x = coords[i*4+3];
  int p = (z*H1 + y)*W1 + x;
  if (vgrid[p] == i){
    int r = atomicAdd(cnt, 1);       // compiler wave-aggregates (m20)
    act[r] = p; vox[r] = i; grid1[p] = r;
  }
}

__global__ void gather0_k(const float4* __restrict__ vf, const int* __restrict__ vox,
                          const int* __restrict__ cnt, float4* __restrict__ f0){
  int r = blockIdx.x*blockDim.x + threadIdx.x;
  if (r >= *cnt) return;
  f0[r] = vf[vox[r]];
}

#define FMA4(acc, f, w0, w1, w2, w3)                      \
  acc.x = fmaf(f.x, w0.x, acc.x); acc.y = fmaf(f.x, w0.y, acc.y); \
  acc.z = fmaf(f.x, w0.z, acc.z); acc.w = fmaf(f.x, w0.w, acc.w); \
  acc.x = fmaf(f.y, w1.x, acc.x); acc.y = fmaf(f.y, w1.y, acc.y); \
  acc.z = fmaf(f.y, w1.z, acc.z); acc.w = fmaf(f.y, w1.w, acc.w); \
  acc.x = fmaf(f.z, w2.x, acc.x); acc.y = fmaf(f.z, w2.y, acc.y); \
  acc.z = fmaf(f.z, w2.z, acc.z); acc.w = fmaf(f.z, w2.w, acc.w); \
  acc.x = fmaf(f.w, w3.x, acc.x); acc.y = fmaf(f.w, w3.y, acc.y); \
  acc.z = fmaf(f.w, w3.z, acc.z); acc.w = fmaf(f.w, w3.w, acc.w)

// ==== VALU sparse/subm conv (R6 structure), used for conv1a only ====
template<int CIN,int COUT,bool SUBM,int DI,int HI,int WI,int HOo,int WOo,
         int SD,int SH,int SW,bool HLOUT>
__global__ __launch_bounds__(256) void conv_sw_k(
    const float* __restrict__ fin, const float* __restrict__ w,
    const float* __restrict__ bnp, const int* __restrict__ grid,
    const int* __restrict__ act, const int* __restrict__ cnt,
    void* __restrict__ fout_v)
{
  constexpr int NT  = 27;
  constexpr int NCO = 8;
  constexpr int NCG = COUT/NCO;
  const int lane = threadIdx.x & 63;
  const int wgl  = blockIdx.x*4 + (threadIdx.x >> 6);
  const int sblk = wgl / NCG;
  const int cg   = wgl % NCG;
  int co = __builtin_amdgcn_readfirstlane(cg*NCO);
  const int n = *cnt;
  if (sblk*64 >= n) return;
  const int r = sblk*64 + lane;
  const bool ok = r < n;

  int z=0, y=0, x=0;
  if (ok){ int p = act[r]; x = p % WOo; int t1 = p/WOo; y = t1 % HOo; z = t1/HOo; }

  auto gidx = [&](int kk)->int {
    if (!ok) return -1;
    int kd = kk/9, kh = (kk/3)%3, kw2 = kk%3;
    if (SUBM){
      if (kk == 13) return r;
      int zz = z + kd - 1, yy = y + kh - 1, xx = x + kw2 - 1;
      if ((unsigned)zz >= (unsigned)DI || (unsigned)yy >= (unsigned)HI ||
          (unsigned)xx >= (unsigned)WI) return -1;
      return grid[(zz*HI + yy)*WI + xx];
    } else {
      int zz = z*SD + kd, yy = y*SH + kh, xx = x*SW + kw2;
      return grid[(zz*HI + yy)*WI + xx];
    }
  };

  float4 acc0 = {0.f,0.f,0.f,0.f}, acc1 = {0.f,0.f,0.f,0.f};
  int rr0 = gidx(0);
  int rr1 = gidx(1);
  #pragma unroll 1
  for (int kk = 0; kk < NT; kk++){
    int rrn = (kk + 2 < NT) ? gidx(kk+2) : -1;
    if (rr0 >= 0){
      const float4* fi = (const float4*)(fin + (size_t)rr0*CIN);
      const float* wt = w + (size_t)kk*CIN*COUT + co;
      #pragma unroll 8
      for (int c4 = 0; c4 < CIN/4; c4++){
        float4 f  = fi[c4];
        const float* wq = wt + c4*4*COUT;
        {
          float4 w0 = *(const float4*)(wq);
          float4 w1 = *(const float4*)(wq + COUT);
          float4 w2 = *(const float4*)(wq + 2*COUT);
          float4 w3 = *(const float4*)(wq + 3*COUT);
          FMA4(acc0, f, w0, w1, w2, w3);
        }
        {
          float4 w0 = *(const float4*)(wq + 4);
          float4 w1 = *(const float4*)(wq + COUT + 4);
          float4 w2 = *(const float4*)(wq + 2*COUT + 4);
          float4 w3 = *(const float4*)(wq + 3*COUT + 4);
          FMA4(acc1, f, w0, w1, w2, w3);
        }
      }
    }
    rr0 = rr1; rr1 = rrn;
  }
  if (ok){
    float o[8];
    float av[8] = {acc0.x,acc0.y,acc0.z,acc0.w, acc1.x,acc1.y,acc1.z,acc1.w};
    #pragma unroll
    for (int k = 0; k < 8; k++){
      int c = co + k;
      float g = bnp[c], b = bnp[COUT+c], m = bnp[2*COUT+c], v = bnp[3*COUT+c];
      o[k] = fmaxf((av[k] - m) * (g * rsqrtf(v + EPSV)) + b, 0.f);
    }
    if constexpr (HLOUT){
      unsigned short* fout = (unsigned short*)fout_v;
      bf16x8 vh, vl;
      #pragma unroll
      for (int k = 0; k < 8; k++){
        unsigned short hi = bf_rne(o[k]);
        vh[k] = (short)hi;
        vl[k] = (short)bf_rne(o[k] - bf_tof(hi));
      }
      *(bf16x8*)(fout + (size_t)r*2*COUT + co) = vh;
      *(bf16x8*)(fout + (size_t)r*2*COUT + COUT + co) = vl;
    } else {
      float* fout = (float*)fout_v;
      float4 o0 = {o[0],o[1],o[2],o[3]}, o1 = {o[4],o[5],o[6],o[7]};
      *(float4*)(fout + (size_t)r*COUT + co) = o0;
      *(float4*)(fout + (size_t)r*COUT + co + 4) = o1;
    }
  }
}

// ---- weight prep: fp32 [27][CIN][COUT] -> bf16 hi/lo packed in B-fragment order
//      flat idx = ((c*COUT + n)*4 + kgrp)*8 + j ; k = c*32 + kgrp*8 + j
//      zero-pads k >= 27*CIN (e.g. CIN=16: K 432 -> 448)
__global__ void wprep_k(const float* __restrict__ w, unsigned short* __restrict__ whi,
                        unsigned short* __restrict__ wlo, int CIN_, int COUT_, int NK_){
  int tid = blockIdx.x*256 + threadIdx.x;
  int total = NK_*COUT_*32;
  if (tid >= total) return;
  int j = tid & 7; int kgrp = (tid>>3)&3; int rest = tid>>5;
  int nn = rest % COUT_; int c = rest / COUT_;
  int kflat = c*32 + kgrp*8 + j;
  if (kflat >= 27*CIN_){ whi[tid] = 0; wlo[tid] = 0; return; }
  int tap = kflat / CIN_; int cin = kflat % CIN_;
  float val = w[((size_t)tap*CIN_ + cin)*COUT_ + nn];
  unsigned short hi = bf_rne(val);
  whi[tid] = hi;
  wlo[tid] = bf_rne(val - bf_tof(hi));
}

// ==== MFMA implicit-GEMM sparse/subm conv, bf16 hi/lo split (3-pass) ====
// Block: 64 sites x COUT. 4 waves. Input/output rows: [hi CIN | lo CIN] bf16.
// CIN in {16,32,64}; K zero-padded to NK*32.
template<int CIN,int COUT,bool SUBM,int DI,int HI,int WI,int HOo,int WOo,
         int SD,int SH,int SW>
__global__ __launch_bounds__(256) void conv_mfma_k(
    const unsigned short* __restrict__ fin, const unsigned short* __restrict__ wBhi,
    const unsigned short* __restrict__ wBlo, const float* __restrict__ bnp,
    const int* __restrict__ grid, const int* __restrict__ act,
    const int* __restrict__ cnt, unsigned short* __restrict__ fout)
{
  constexpr int NK  = (27*CIN + 31)/32;  // K chunks of 32 (zero-padded)
  constexpr int NTN = COUT/16;           // n-tiles in block
  constexpr int MT  = (NTN > 1) ? NTN : 1;  // m-tiles per wave
  constexpr int LDA = 40;                // ushort stride per A chunk-row (80B)
  __shared__ int act_lds[64];
  __shared__ int rr_lds[27*64];
  __shared__ unsigned short AhiL[2][64*LDA];
  __shared__ unsigned short AloL[2][64*LDA];

  const int tid  = threadIdx.x;
  const int lane = tid & 63;
  const int wv   = tid >> 6;
  const int blk  = blockIdx.x;
  const int n    = *cnt;
  if (blk*64 >= n) return;

  if (tid < 64){
    int r = blk*64 + tid;
    act_lds[tid] = (r < n) ? act[r] : -1;
  }
  __syncthreads();
  for (int idx = tid; idx < 27*64; idx += 256){
    int s = idx & 63, tap = idx >> 6;
    int p = act_lds[s];
    int rr = -1;
    if (p >= 0){
      int x = p % WOo; int t1 = p / WOo; int y = t1 % HOo; int z = t1 / HOo;
      int kd = tap/9, kh = (tap/3)%3, kw2 = tap%3;
      if (SUBM){
        if (tap == 13) rr = blk*64 + s;
        else {
          int zz = z+kd-1, yy = y+kh-1, xx = x+kw2-1;
          if ((unsigned)zz < (unsigned)DI && (unsigned)yy < (unsigned)HI &&
              (unsigned)xx < (unsigned)WI)
            rr = grid[(zz*HI+yy)*WI+xx];
        }
      } else {
        int zz = z*SD+kd, yy = y*SH+kh, xx = x*SW+kw2;
        rr = grid[(zz*HI+yy)*WI+xx];
      }
    }
    rr_lds[idx] = rr;
  }
  __syncthreads();

  const int ss = tid >> 2;          // staging site
  const int sq = tid & 3;           // staging quarter (0,1=hi; 2,3=lo)
  const bf16x8 zv = {0,0,0,0,0,0,0,0};

  // generalized segment mapping: 16-wide segment at k = c*32 + (sq&1)*16
  auto stage_load = [&](int c, bf16x8& v0, bf16x8& v1){
    int kseg = c*32 + (sq&1)*16;
    int tap  = kseg / CIN;
    int ch   = kseg % CIN;
    int rr   = (tap < 27) ? rr_lds[tap*64 + ss] : -1;
    if (rr >= 0){
      int eoff = (sq < 2) ? ch : (CIN + ch);
      const bf16x8* sp = (const bf16x8*)(fin + (size_t)rr*2*CIN + eoff);
      v0 = sp[0]; v1 = sp[1];
    } else { v0 = zv; v1 = zv; }
  };
  auto stage_write = [&](int b, bf16x8 v0, bf16x8 v1){
    unsigned short* base = (sq < 2) ? &AhiL[b][ss*LDA + (sq&1)*16]
                                    : &AloL[b][ss*LDA + (sq&1)*16];
    ((bf16x8*)base)[0] = v0; ((bf16x8*)base)[1] = v1;
  };

  const int nt    = wv % NTN;
  const int mbase = (wv / NTN) * MT;
  const int l15   = lane & 15;
  const int lg    = lane >> 4;

  f32x4 acc[MT];
  #pragma unroll
  for (int i = 0; i < MT; i++) acc[i] = (f32x4){0.f,0.f,0.f,0.f};

  {
    bf16x8 s0, s1;
    stage_load(0, s0, s1);
    stage_write(0, s0, s1);
  }
  __syncthreads();

  #pragma unroll 1
  for (int c = 0; c < NK; c++){
    const int b = c & 1;
    bf16x8 n0 = zv, n1 = zv;
    if (c + 1 < NK) stage_load(c+1, n0, n1);

    // B fragments (global, packed): lane -> n = nt*16+l15, kgrp = lg
    size_t bidx = ((size_t)(c*COUT + nt*16 + l15)*4 + lg) * 8;
    bf16x8 Bh = *(const bf16x8*)(wBhi + bidx);
    bf16x8 Bl = *(const bf16x8*)(wBlo + bidx);

    #pragma unroll
    for (int i = 0; i < MT; i++){
      int row = (mbase + i)*16 + l15;
      bf16x8 Ah = *(const bf16x8*)(&AhiL[b][row*LDA + lg*8]);
      bf16x8 Al = *(const bf16x8*)(&AloL[b][row*LDA + lg*8]);
      acc[i] = __builtin_amdgcn_mfma_f32_16x16x32_bf16(Ah, Bh, acc[i], 0, 0, 0);
      acc[i] = __builtin_amdgcn_mfma_f32_16x16x32_bf16(Ah, Bl, acc[i], 0, 0, 0);
      acc[i] = __builtin_amdgcn_mfma_f32_16x16x32_bf16(Al, Bh, acc[i], 0, 0, 0);
    }

    if (c + 1 < NK) stage_write(b ^ 1, n0, n1);
    __syncthreads();
  }

  // epilogue: D row = mtile*16 + (lane>>4)*4 + reg (site), col = nt*16 + (lane&15)
  const int cout = nt*16 + l15;
  const float g = bnp[cout], bb = bnp[COUT+cout];
  const float mm = bnp[2*COUT+cout], vv = bnp[3*COUT+cout];
  const float sc = g * rsqrtf(vv + EPSV);
  #pragma unroll
  for (int i = 0; i < MT; i++){
    #pragma unroll
    for (int reg = 0; reg < 4; reg++){
      int srow = (mbase + i)*16 + lg*4 + reg;
      int r = blk*64 + srow;
      if (r < n){
        float o = fmaxf((acc[i][reg] - mm) * sc + bb, 0.f);
        unsigned short hi = bf_rne(o);
        unsigned short lo = bf_rne(o - bf_tof(hi));
        fout[(size_t)r*2*COUT + cout] = hi;
        fout[(size_t)r*2*COUT + COUT + cout] = lo;
      }
    }
  }
}

// ---- build downsampled active list ----
template<int DI,int HI,int WI,int DDo,int HHo,int WWo,int KD,int KH,int KW,int SD,int SH,int SW>
__global__ void build_k(const int* __restrict__ gin, int* __restrict__ gout,
                        int* __restrict__ act, int* __restrict__ cnt){
  __shared__ int lcnt, lbase;
  if (threadIdx.x == 0) lcnt = 0;
  __syncthreads();
  int p = blockIdx.x*blockDim.x + threadIdx.x;
  bool any = false;
  if (p < DDo*HHo*WWo){
    int x = p % WWo; int rem = p / WWo; int y = rem % HHo; int z = rem / HHo;
    for (int kd = 0; kd < KD; kd++)
      for (int kh = 0; kh < KH; kh++)
        for (int kw = 0; kw < KW; kw++){
          if (gin[((z*SD+kd)*HI + (y*SH+kh))*WI + (x*SW+kw)] >= 0) any = true;
        }
  }
  int loc = -1;
  if (any) loc = atomicAdd(&lcnt, 1);
  __syncthreads();
  if (threadIdx.x == 0) lbase = (lcnt > 0) ? atomicAdd(cnt, lcnt) : 0;
  __syncthreads();
  if (p < DDo*HHo*WWo){
    int r = any ? (lbase + loc) : -1;
    if (any) act[r] = p;
    gout[p] = r;
  }
}

// ---- final conv (3,1,1) VALID, dense out; reads hi/lo bf16 f4b ----
__global__ __launch_bounds__(256) void out_conv_k(
    const unsigned short* __restrict__ f4, const float* __restrict__ w,
    const float* __restrict__ bnp, const int* __restrict__ g4,
    float* __restrict__ out){
  int t = blockIdx.x*blockDim.x + threadIdx.x;
  if (t >= SO_*32) return;
  int co = (t % 32)*4; int p = t / 32;
  int x = p % WO_; int rem = p / WO_; int y = rem % HO_; int z = rem / HO_;
  bool any = false; float4 acc = {0.f,0.f,0.f,0.f};
  for (int kd = 0; kd < 3; kd++){
    int rr = g4[((z+kd)*H4 + y)*W4 + x];
    if (rr < 0) continue;
    any = true;
    const unsigned short* row = f4 + (size_t)rr*128;
    const float* wp = w + (size_t)kd*64*128 + co;
    #pragma unroll 4
    for (int ci = 0; ci < 64; ci++){
      float f = bf_tof(row[ci]) + bf_tof(row[64+ci]);
      const float* wq = wp + (size_t)ci*128;
      acc.x = fmaf(f, wq[0], acc.x); acc.y = fmaf(f, wq[1], acc.y);
      acc.z = fmaf(f, wq[2], acc.z); acc.w = fmaf(f, wq[3], acc.w);
    }
  }
  float4 o = {0.f,0.f,0.f,0.f};
  if (any){
    float4 g = *(const float4*)(bnp + co);
    float4 b = *(const float4*)(bnp + 128 + co);
    float4 m = *(const float4*)(bnp + 2*128 + co);
    float4 v = *(const float4*)(bnp + 3*128 + co);
    o.x = fmaxf((acc.x - m.x) * (g.x * rsqrtf(v.x + EPSV)) + b.x, 0.f);
    o.y = fmaxf((acc.y - m.y) * (g.y * rsqrtf(v.y + EPSV)) + b.y, 0.f);
    o.z = fmaxf((acc.z - m.z) * (g.z * rsqrtf(v.z + EPSV)) + b.z, 0.f);
    o.w = fmaxf((acc.w - m.w) * (g.w * rsqrtf(v.w + EPSV)) + b.w, 0.f);
  }
  *(float4*)(out + (size_t)p*128 + co) = o;
}

extern "C" void kernel_launch(void* const* d_in, const int* in_sizes, int n_in,
                              void* d_out, int out_size, void* d_ws, size_t ws_size,
                              hipStream_t stream){
  const float* vf  = (const float*)d_in[0];
  const int*   vc  = (const int*)  d_in[1];
  const float* w1a = (const float*)d_in[2];  const float* bn1a = (const float*)d_in[3];
  const float* w1b = (const float*)d_in[4];  const float* bn1b = (const float*)d_in[5];
  const float* w2a = (const float*)d_in[6];  const float* bn2a = (const float*)d_in[7];
  const float* w2b = (const float*)d_in[8];  const float* bn2b = (const float*)d_in[9];
  const float* w3a = (const float*)d_in[10]; const float* bn3a = (const float*)d_in[11];
  const float* w3b = (const float*)d_in[12]; const float* bn3b = (const float*)d_in[13];
  const float* w4a = (const float*)d_in[14]; const float* bn4a = (const float*)d_in[15];
  const float* w4b = (const float*)d_in[16]; const float* bn4b = (const float*)d_in[17];
  const float* wo  = (const float*)d_in[18]; const float* bno  = (const float*)d_in[19];
  float* outp = (float*)d_out;
  int nvox = in_sizes[0] / 4;
  if (nvox > NVOX_MAX) nvox = NVOX_MAX;

  char* ws = (char*)d_ws;
  size_t off = 0;
  auto alloc = [&](size_t bytes)->void*{
    void* p = ws + off; off = (off + bytes + 255) & ~size_t(255); return p;
  };
  int* vgrid = (int*)alloc((size_t)S1*4);
  int* grid1 = (int*)alloc((size_t)S1*4);
  int* act1  = (int*)alloc((size_t)NVOX_MAX*4);
  int* vox1  = (int*)alloc((size_t)NVOX_MAX*4);
  int* grid2 = (int*)alloc((size_t)S2*4);
  int* act2  = (int*)alloc((size_t)S2*4);
  int* grid3 = (int*)alloc((size_t)S3*4);
  int* act3  = (int*)alloc((size_t)S3*4);
  int* grid4 = (int*)alloc((size_t)S4*4);
  int* act4  = (int*)alloc((size_t)S4*4);
  int* cnt   = (int*)alloc(8*4);
  size_t f0_b  = (size_t)NVOX_MAX*4*4;
  size_t f1_b  = (size_t)NVOX_MAX*32*2;   // bf16 [hi16|lo16]
  size_t f2_b  = (size_t)S2*64*2;         // bf16 [hi32|lo32]
  size_t f3_b  = (size_t)S3*128*2;        // bf16 [hi64|lo64]
  size_t f4_b  = (size_t)S4*128*2;
  float* f0  = (float*)alloc(f0_b);
  unsigned short* f1a = (unsigned short*)alloc(f1_b);
  unsigned short* f1b = (unsigned short*)alloc(f1_b);
  unsigned short* f2a = (unsigned short*)alloc(f2_b);
  unsigned short* f2b = (unsigned short*)alloc(f2_b);
  unsigned short* f3a = (unsigned short*)alloc(f3_b);
  unsigned short* f3b = (unsigned short*)alloc(f3_b);
  unsigned short* f4a = (unsigned short*)alloc(f4_b);
  unsigned short* f4b = (unsigned short*)alloc(f4_b);
  // packed B-fragment weights (hi/lo); NK: CIN=16 -> 14, CIN=32 -> 27, CIN=64 -> 54
  unsigned short* p1b_h = (unsigned short*)alloc((size_t)14*32*16*2);
  unsigned short* p1b_l = (unsigned short*)alloc((size_t)14*32*16*2);
  unsigned short* p2a_h = (unsigned short*)alloc((size_t)14*32*32*2);
  unsigned short* p2a_l = (unsigned short*)alloc((size_t)14*32*32*2);
  unsigned short* p2b_h = (unsigned short*)alloc((size_t)27*32*32*2);
  unsigned short* p2b_l = (unsigned short*)alloc((size_t)27*32*32*2);
  unsigned short* p3a_h = (unsigned short*)alloc((size_t)27*32*64*2);
  unsigned short* p3a_l = (unsigned short*)alloc((size_t)27*32*64*2);
  unsigned short* p3b_h = (unsigned short*)alloc((size_t)54*32*64*2);
  unsigned short* p3b_l = (unsigned short*)alloc((size_t)54*32*64*2);
  unsigned short* p4a_h = (unsigned short*)alloc((size_t)54*32*64*2);
  unsigned short* p4a_l = (unsigned short*)alloc((size_t)54*32*64*2);
  unsigned short* p4b_h = (unsigned short*)alloc((size_t)54*32*64*2);
  unsigned short* p4b_l = (unsigned short*)alloc((size_t)54*32*64*2);
  (void)ws_size;

  hipMemsetAsync(vgrid, 0xFF, (size_t)S1*4, stream);
  hipMemsetAsync(grid1, 0xFF, (size_t)S1*4, stream);
  hipMemsetAsync(cnt, 0, 8*4, stream);
  // Zero all intermediate feature buffers (R10 lesson: deterministic replays)
  hipMemsetAsync(f0,  0, f0_b, stream);
  hipMemsetAsync(f1a, 0, f1_b, stream);
  hipMemsetAsync(f1b, 0, f1_b, stream);
  hipMemsetAsync(f2a, 0, f2_b, stream);
  hipMemsetAsync(f2b, 0, f2_b, stream);
  hipMemsetAsync(f3a, 0, f3_b, stream);
  hipMemsetAsync(f3b, 0, f3_b, stream);
  hipMemsetAsync(f4a, 0, f4_b, stream);
  hipMemsetAsync(f4b, 0, f4_b, stream);

  const int BS = 256;
  auto wprep = [&](const float* w, unsigned short* h, unsigned short* l, int cin, int cout, int nk){
    int total = nk*cout*32;
    wprep_k<<<(total+BS-1)/BS, BS, 0, stream>>>(w, h, l, cin, cout, nk);
  };
  wprep(w1b, p1b_h, p1b_l, 16, 16, 14);
  wprep(w2a, p2a_h, p2a_l, 16, 32, 14);
  wprep(w2b, p2b_h, p2b_l, 32, 32, 27);
  wprep(w3a, p3a_h, p3a_l, 32, 64, 27);
  wprep(w3b, p3b_h, p3b_l, 64, 64, 54);
  wprep(w4a, p4a_h, p4a_l, 64, 64, 54);
  wprep(w4b, p4b_h, p4b_l, 64, 64, 54);

  scatter_k<<<(nvox+BS-1)/BS, BS, 0, stream>>>(vc, nvox, vgrid);
  compactv_k<<<(nvox+BS-1)/BS, BS, 0, stream>>>(vc, nvox, vgrid, grid1, act1, vox1, &cnt[0]);
  gather0_k<<<(nvox+BS-1)/BS, BS, 0, stream>>>((const float4*)vf, vox1, &cnt[0], (float4*)f0);

  auto nblk = [](int maxN, int cout){ int waves = ((maxN+63)/64) * (cout/8); return (waves+3)/4; };

  // conv1a (VALU, CIN=4) -> hi/lo bf16
  conv_sw_k<4,16,true,D1,H1,W1,H1,W1,1,1,1,true>
    <<<nblk(NVOX_MAX,16), BS, 0, stream>>>(f0, w1a, bn1a, grid1, act1, &cnt[0], f1a);
  // conv1b (MFMA, CIN=16, K padded 432->448)
  conv_mfma_k<16,16,true,D1,H1,W1,H1,W1,1,1,1>
    <<<(NVOX_MAX+63)/64, BS, 0, stream>>>(f1a, p1b_h, p1b_l, bn1b, grid1, act1, &cnt[0], f1b);

  build_k<D1,H1,W1,D2,H2,W2,3,3,3,2,2,2><<<(S2+BS-1)/BS, BS, 0, stream>>>(grid1, grid2, act2, &cnt[1]);
  // conv2a (MFMA, CIN=16, strided)
  conv_mfma_k<16,32,false,D1,H1,W1,H2,W2,2,2,2>
    <<<(S2+63)/64, BS, 0, stream>>>(f1b, p2a_h, p2a_l, bn2a, grid1, act2, &cnt[1], f2a);
  // conv2b (MFMA)
  conv_mfma_k<32,32,true,D2,H2,W2,H2,W2,1,1,1>
    <<<(S2+63)/64, BS, 0, stream>>>(f2a, p2b_h, p2b_l, bn2b, grid2, act2, &cnt[1], f2b);

  build_k<D2,H2,W2,D3,H3,W3,3,3,3,2,2,2><<<(S3+BS-1)/BS, BS, 0, stream>>>(grid2, grid3, act3, &cnt[2]);
  conv_mfma_k<32,64,false,D2,H2,W2,H3,W3,2,2,2>
    <<<(S3+63)/64, BS, 0, stream>>>(f2b, p3a_h, p3a_l, bn3a, grid2, act3, &cnt[2], f3a);
  conv_mfma_k<64,64,true,D3,H3,W3,H3,W3,1,1,1>
    <<<(S3+63)/64, BS, 0, stream>>>(f3a, p3b_h, p3b_l, bn3b, grid3, act3, &cnt[2], f3b);

  build_k<D3,H3,W3,D4,H4,W4,3,3,3,2,2,2><<<(S4+BS-1)/BS, BS, 0, stream>>>(grid3, grid4, act4, &cnt[3]);
  conv_mfma_k<64,64,false,D3,H3,W3,H4,W4,2,2,2>
    <<<(S4+63)/64, BS, 0, stream>>>(f3b, p4a_h, p4a_l, bn4a, grid3, act4, &cnt[3], f4a);
  conv_mfma_k<64,64,true,D4,H4,W4,H4,W4,1,1,1>
    <<<(S4+63)/64, BS, 0, stream>>>(f4a, p4b_h, p4b_l, bn4b, grid4, act4, &cnt[3], f4b);

  out_conv_k<<<(SO_*32+BS-1)/BS, BS, 0, stream>>>(f4b, wo, bno, grid4, outp);
}